// Round 1
// baseline (1208.458 us; speedup 1.0000x reference)
//
#include <hip/hip_runtime.h>
#include <math.h>

#define N_VAR 8192
#define N_CHK 4096
#define DV 3
#define N_EDGE (N_VAR * DV)
#define BATCH 128
#define T_ITERS 30
#define EPS_F 1e-7f
#define DEGMAX 32

// ---------------- CSR build (once per launch; edge_chk is random) ----------

__global__ void k_count(const int* __restrict__ edge_chk, int* __restrict__ counts) {
    int e = blockIdx.x * blockDim.x + threadIdx.x;
    if (e < N_EDGE) atomicAdd(&counts[edge_chk[e]], 1);
}

// 1 block, 1024 threads, 4 elements/thread -> exclusive prefix over 4096 counts
__global__ __launch_bounds__(1024) void k_scan(const int* __restrict__ counts,
                                               int* __restrict__ ptr,
                                               int* __restrict__ fill) {
    __shared__ int bufA[1024];
    __shared__ int bufB[1024];
    int t = threadIdx.x;
    int c0 = counts[4 * t + 0];
    int c1 = counts[4 * t + 1];
    int c2 = counts[4 * t + 2];
    int c3 = counts[4 * t + 3];
    int s = c0 + c1 + c2 + c3;
    bufA[t] = s;
    __syncthreads();
    int* src = bufA;
    int* dst = bufB;
    for (int off = 1; off < 1024; off *= 2) {
        int v = src[t];
        if (t >= off) v += src[t - off];
        dst[t] = v;
        __syncthreads();
        int* tmp = src; src = dst; dst = tmp;
    }
    int incl = src[t];
    int excl = incl - s;
    int p0 = excl, p1 = excl + c0, p2 = excl + c0 + c1, p3 = excl + c0 + c1 + c2;
    ptr[4 * t + 0] = p0;  fill[4 * t + 0] = p0;
    ptr[4 * t + 1] = p1;  fill[4 * t + 1] = p1;
    ptr[4 * t + 2] = p2;  fill[4 * t + 2] = p2;
    ptr[4 * t + 3] = p3;  fill[4 * t + 3] = p3;
    if (t == 1023) ptr[N_CHK] = incl;
}

__global__ void k_scatter(const int* __restrict__ edge_chk, int* __restrict__ fill,
                          int* __restrict__ edges) {
    int e = blockIdx.x * blockDim.x + threadIdx.x;
    if (e < N_EDGE) {
        int c = edge_chk[e];
        int pos = atomicAdd(&fill[c], 1);
        edges[pos] = e;
    }
}

// ---------------- Variable-node update (edge_var[e] = e/3, contiguous) -----
// Computes varsum over current msg_C2V; writes out[iter-1] (posterior of the
// previous iteration); damped V2C update.

__global__ __launch_bounds__(256) void k_var(const float* __restrict__ chn,
                                             const float* __restrict__ gamma_logit,
                                             const float* __restrict__ msg_C2V,
                                             float* __restrict__ msg_V2C,
                                             float* __restrict__ out, int iter) {
    int gid = blockIdx.x * 256 + threadIdx.x;
    int v = gid >> 7;        // / BATCH
    int b = gid & 127;       // % BATCH
    float g = 1.0f / (1.0f + expf(-gamma_logit[0]));   // sigmoid; 0 -> exactly 0.5
    float om = 1.0f - g;

    int e0 = v * DV;
    int i0 = (e0 + 0) * BATCH + b;
    int i1 = (e0 + 1) * BATCH + b;
    int i2 = (e0 + 2) * BATCH + b;
    float c0 = msg_C2V[i0];
    float c1 = msg_C2V[i1];
    float c2 = msg_C2V[i2];
    float vs = c0 + c1 + c2;
    float ch = chn[v * BATCH + b];
    if (iter > 0) {
        out[(size_t)(iter - 1) * (N_VAR * BATCH) + v * BATCH + b] = ch + vs;
    }
    float tot = ch + vs;
    float o0 = msg_V2C[i0];
    float o1 = msg_V2C[i1];
    float o2 = msg_V2C[i2];
    msg_V2C[i0] = g * (tot - c0) + om * o0;
    msg_V2C[i1] = g * (tot - c1) + om * o1;
    msg_V2C[i2] = g * (tot - c2) + om * o2;
}

// ---------------- Check-node update (block per check, thread per batch) ----

__global__ __launch_bounds__(128) void k_chk(const float* __restrict__ msg_V2C,
                                             float* __restrict__ msg_C2V,
                                             const int* __restrict__ ptr,
                                             const int* __restrict__ edges) {
    __shared__ float lds_la[DEGMAX * BATCH];   // 16 KiB
    int c = blockIdx.x;
    int b = threadIdx.x;
    int p0 = ptr[c];
    int deg = ptr[c + 1] - p0;

    float sum_log = 0.0f;
    unsigned mask = 0u;
    int hi_neg = 0;   // fallback for deg > DEGMAX (statistically never triggers)

    for (int j = 0; j < deg; ++j) {
        int e = edges[p0 + j];
        float x = msg_V2C[e * BATCH + b];
        x = fminf(fmaxf(x, -15.0f), 15.0f);
        float t = tanhf(0.5f * x);
        float la = logf(fmaxf(fabsf(t), EPS_F));
        sum_log += la;
        int neg = (t < 0.0f) ? 1 : 0;
        if (j < DEGMAX) {
            lds_la[j * BATCH + b] = la;
            mask |= (unsigned)neg << j;
        } else {
            hi_neg += neg;
        }
    }
    int totneg = __popc(mask) + hi_neg;

    const float clip_hi = 1.0f - 1e-7f;
    const float clip_lo = -1.0f + 1e-7f;
    for (int j = 0; j < deg; ++j) {
        int e = edges[p0 + j];
        float la;
        int neg;
        if (j < DEGMAX) {
            la = lds_la[j * BATCH + b];
            neg = (mask >> j) & 1;
        } else {
            float x = msg_V2C[e * BATCH + b];
            x = fminf(fmaxf(x, -15.0f), 15.0f);
            float t = tanhf(0.5f * x);
            la = logf(fmaxf(fabsf(t), EPS_F));
            neg = (t < 0.0f) ? 1 : 0;
        }
        float ext_log = sum_log - la;
        int par = (totneg - neg) & 1;
        float sgn = 1.0f - 2.0f * (float)par;
        float p = sgn * expf(ext_log);
        p = fminf(fmaxf(p, clip_lo), clip_hi);
        msg_C2V[e * BATCH + b] = 2.0f * atanhf(p);
    }
}

// ---------------- Final posterior (out[T-1]) -------------------------------

__global__ __launch_bounds__(256) void k_out_final(const float* __restrict__ chn,
                                                   const float* __restrict__ msg_C2V,
                                                   float* __restrict__ out) {
    int gid = blockIdx.x * 256 + threadIdx.x;
    int v = gid >> 7;
    int b = gid & 127;
    int e0 = v * DV;
    float vs = msg_C2V[(e0 + 0) * BATCH + b] + msg_C2V[(e0 + 1) * BATCH + b] +
               msg_C2V[(e0 + 2) * BATCH + b];
    out[(size_t)(T_ITERS - 1) * (N_VAR * BATCH) + v * BATCH + b] =
        chn[v * BATCH + b] + vs;
}

// ---------------- Launch ---------------------------------------------------

extern "C" void kernel_launch(void* const* d_in, const int* in_sizes, int n_in,
                              void* d_out, int out_size, void* d_ws, size_t ws_size,
                              hipStream_t stream) {
    const float* chn         = (const float*)d_in[0];
    const float* gamma_logit = (const float*)d_in[1];
    // d_in[2] = edge_var (deterministic: e/3) — not needed
    const int* edge_chk      = (const int*)d_in[3];
    float* out = (float*)d_out;

    float* msg_C2V = (float*)d_ws;
    float* msg_V2C = msg_C2V + (size_t)N_EDGE * BATCH;
    int* counts = (int*)(msg_V2C + (size_t)N_EDGE * BATCH);
    int* ptr    = counts + N_CHK;
    int* fill   = ptr + (N_CHK + 1);
    int* edges  = fill + N_CHK;

    // zero message state + counts (ws is poisoned before every call)
    hipMemsetAsync(msg_C2V, 0, 2 * sizeof(float) * (size_t)N_EDGE * BATCH, stream);
    hipMemsetAsync(counts, 0, sizeof(int) * N_CHK, stream);

    k_count<<<(N_EDGE + 255) / 256, 256, 0, stream>>>(edge_chk, counts);
    k_scan<<<1, 1024, 0, stream>>>(counts, ptr, fill);
    k_scatter<<<(N_EDGE + 255) / 256, 256, 0, stream>>>(edge_chk, fill, edges);

    for (int t = 0; t < T_ITERS; ++t) {
        k_var<<<(N_VAR * BATCH) / 256, 256, 0, stream>>>(chn, gamma_logit, msg_C2V,
                                                         msg_V2C, out, t);
        k_chk<<<N_CHK, 128, 0, stream>>>(msg_V2C, msg_C2V, ptr, edges);
    }
    k_out_final<<<(N_VAR * BATCH) / 256, 256, 0, stream>>>(chn, msg_C2V, out);
}

// Round 3
// 778.894 us; speedup vs baseline: 1.5515x; 1.5515x over previous
//
#include <hip/hip_runtime.h>
#include <math.h>

#define N_VAR 8192
#define N_CHK 4096
#define DV 3
#define N_EDGE (N_VAR * DV)
#define BATCH 128
#define T_ITERS 30
#define EPS_F 1e-7f
#define DEGMAX 24

#define LOG2E 1.44269504088896340736f
#define LN2   0.69314718055994530942f
#define LN_EPS -16.118095651f   /* ln(1e-7) */

typedef float v4f __attribute__((ext_vector_type(4)));

__device__ __forceinline__ float fast_exp(float x) {   // e^x
    return __builtin_amdgcn_exp2f(x * LOG2E);
}

// log|tanh(x/2)| with x pre-clipped to [-15,15]; u = |x|
__device__ __forceinline__ float log_tanh_half(float u) {
    float E = __builtin_amdgcn_exp2f(-u * LOG2E);          // e^-u
    float la_big = (__builtin_amdgcn_logf(1.0f - E) -
                    __builtin_amdgcn_logf(1.0f + E)) * LN2;
    // small-u: tanh(z) = z(1 - z^2/3 + 2 z^4/15), z = u/2  (rel err < 5e-7 for u<0.25)
    float z = 0.5f * u;
    float zz = z * z;
    float ts = z * (1.0f - zz * (0.33333333f - 0.13333333f * zz));
    float la_small = __builtin_amdgcn_logf(ts) * LN2;
    float la = (u < 0.25f) ? la_small : la_big;
    return fmaxf(la, LN_EPS);
}

// 2*atanh(e^L) for L <= ~0, clipped like the reference
__device__ __forceinline__ float back_transform(float L) {
    float p = __builtin_amdgcn_exp2f(L * LOG2E);
    p = fminf(p, 1.0f - 1e-7f);
    return (__builtin_amdgcn_logf(1.0f + p) -
            __builtin_amdgcn_logf(1.0f - p)) * LN2;
}

// ---------------- CSR build (once per launch; edge_chk is random) ----------

__global__ void k_count(const int* __restrict__ edge_chk, int* __restrict__ counts) {
    int e = blockIdx.x * blockDim.x + threadIdx.x;
    if (e < N_EDGE) atomicAdd(&counts[edge_chk[e]], 1);
}

__global__ __launch_bounds__(1024) void k_scan(const int* __restrict__ counts,
                                               int* __restrict__ ptr,
                                               int* __restrict__ fill) {
    __shared__ int bufA[1024];
    __shared__ int bufB[1024];
    int t = threadIdx.x;
    int c0 = counts[4 * t + 0];
    int c1 = counts[4 * t + 1];
    int c2 = counts[4 * t + 2];
    int c3 = counts[4 * t + 3];
    int s = c0 + c1 + c2 + c3;
    bufA[t] = s;
    __syncthreads();
    int* src = bufA;
    int* dst = bufB;
    for (int off = 1; off < 1024; off *= 2) {
        int v = src[t];
        if (t >= off) v += src[t - off];
        dst[t] = v;
        __syncthreads();
        int* tmp = src; src = dst; dst = tmp;
    }
    int incl = src[t];
    int excl = incl - s;
    int p0 = excl, p1 = excl + c0, p2 = excl + c0 + c1, p3 = excl + c0 + c1 + c2;
    ptr[4 * t + 0] = p0;  fill[4 * t + 0] = p0;
    ptr[4 * t + 1] = p1;  fill[4 * t + 1] = p1;
    ptr[4 * t + 2] = p2;  fill[4 * t + 2] = p2;
    ptr[4 * t + 3] = p3;  fill[4 * t + 3] = p3;
    if (t == 1023) ptr[N_CHK] = incl;
}

__global__ void k_scatter(const int* __restrict__ edge_chk, int* __restrict__ fill,
                          int* __restrict__ edges) {
    int e = blockIdx.x * blockDim.x + threadIdx.x;
    if (e < N_EDGE) {
        int c = edge_chk[e];
        int pos = atomicAdd(&fill[c], 1);
        edges[pos] = e;
    }
}

// ---------------- Variable-node update, float4 over batch ------------------
// thread -> (v, 4 batch elems). Writes out[iter-1] (prev posterior) nontemporal.

__global__ __launch_bounds__(256) void k_var(const float* __restrict__ chn,
                                             const float* __restrict__ gamma_logit,
                                             const float* __restrict__ msg_C2V,
                                             float* __restrict__ msg_V2C,
                                             float* __restrict__ out, int iter) {
    int gid = blockIdx.x * 256 + threadIdx.x;     // 0 .. N_VAR*BATCH/4
    int v = gid >> 5;                              // / 32
    int q = gid & 31;                              // float4 index in batch
    float g = 1.0f / (1.0f + fast_exp(-gamma_logit[0]));
    float om = 1.0f - g;

    const v4f* c2v = (const v4f*)msg_C2V;
    v4f* v2c = (v4f*)msg_V2C;
    int e0 = v * DV;
    int i0 = (e0 + 0) * (BATCH / 4) + q;
    int i1 = (e0 + 1) * (BATCH / 4) + q;
    int i2 = (e0 + 2) * (BATCH / 4) + q;
    v4f c0 = c2v[i0];
    v4f c1 = c2v[i1];
    v4f c2 = c2v[i2];
    v4f ch = ((const v4f*)chn)[v * (BATCH / 4) + q];
    v4f tot = ch + c0 + c1 + c2;
    if (iter > 0) {
        v4f* o = (v4f*)(out + (size_t)(iter - 1) * (N_VAR * BATCH));
        __builtin_nontemporal_store(tot, &o[v * (BATCH / 4) + q]);
    }
    v4f o0 = v2c[i0];
    v4f o1 = v2c[i1];
    v4f o2 = v2c[i2];
    v2c[i0] = g * (tot - c0) + om * o0;
    v2c[i1] = g * (tot - c1) + om * o1;
    v2c[i2] = g * (tot - c2) + om * o2;
}

// ---------------- Check-node update (block per check, thread per batch) ----

__global__ __launch_bounds__(128) void k_chk(const float* __restrict__ msg_V2C,
                                             float* __restrict__ msg_C2V,
                                             const int* __restrict__ ptr,
                                             const int* __restrict__ edges) {
    __shared__ float lds_la[DEGMAX * BATCH];   // 12 KiB
    int c = blockIdx.x;
    int b = threadIdx.x;
    int p0 = ptr[c];
    int deg = ptr[c + 1] - p0;

    float sum_log = 0.0f;
    unsigned mask = 0u;
    int hi_neg = 0;   // fallback for deg > DEGMAX (rare for Poisson(6))

    for (int j = 0; j < deg; ++j) {
        int e = edges[p0 + j];
        float x = msg_V2C[e * BATCH + b];
        x = fminf(fmaxf(x, -15.0f), 15.0f);
        float la = log_tanh_half(fabsf(x));
        sum_log += la;
        int neg = (x < 0.0f) ? 1 : 0;
        if (j < DEGMAX) {
            lds_la[j * BATCH + b] = la;
            mask |= (unsigned)neg << j;
        } else {
            hi_neg += neg;
        }
    }
    int totneg = __popc(mask) + hi_neg;

    for (int j = 0; j < deg; ++j) {
        int e = edges[p0 + j];
        float la;
        int neg;
        if (j < DEGMAX) {
            la = lds_la[j * BATCH + b];
            neg = (mask >> j) & 1;
        } else {
            float x = msg_V2C[e * BATCH + b];
            x = fminf(fmaxf(x, -15.0f), 15.0f);
            la = log_tanh_half(fabsf(x));
            neg = (x < 0.0f) ? 1 : 0;
        }
        float ext_log = sum_log - la;
        int par = (totneg - neg) & 1;
        float m = back_transform(ext_log);
        msg_C2V[e * BATCH + b] = par ? -m : m;
    }
}

// ---------------- Final posterior (out[T-1]) -------------------------------

__global__ __launch_bounds__(256) void k_out_final(const float* __restrict__ chn,
                                                   const float* __restrict__ msg_C2V,
                                                   float* __restrict__ out) {
    int gid = blockIdx.x * 256 + threadIdx.x;
    int v = gid >> 5;
    int q = gid & 31;
    const v4f* c2v = (const v4f*)msg_C2V;
    int e0 = v * DV;
    v4f c0 = c2v[(e0 + 0) * (BATCH / 4) + q];
    v4f c1 = c2v[(e0 + 1) * (BATCH / 4) + q];
    v4f c2 = c2v[(e0 + 2) * (BATCH / 4) + q];
    v4f ch = ((const v4f*)chn)[v * (BATCH / 4) + q];
    v4f tot = ch + c0 + c1 + c2;
    v4f* o = (v4f*)(out + (size_t)(T_ITERS - 1) * (N_VAR * BATCH));
    __builtin_nontemporal_store(tot, &o[v * (BATCH / 4) + q]);
}

// ---------------- Launch ---------------------------------------------------

extern "C" void kernel_launch(void* const* d_in, const int* in_sizes, int n_in,
                              void* d_out, int out_size, void* d_ws, size_t ws_size,
                              hipStream_t stream) {
    const float* chn         = (const float*)d_in[0];
    const float* gamma_logit = (const float*)d_in[1];
    // d_in[2] = edge_var (deterministic: e/3) — not needed
    const int* edge_chk      = (const int*)d_in[3];
    float* out = (float*)d_out;

    float* msg_C2V = (float*)d_ws;
    float* msg_V2C = msg_C2V + (size_t)N_EDGE * BATCH;
    int* counts = (int*)(msg_V2C + (size_t)N_EDGE * BATCH);
    int* ptr    = counts + N_CHK;
    int* fill   = ptr + (N_CHK + 1);
    int* edges  = fill + N_CHK;

    (void)hipMemsetAsync(msg_C2V, 0, 2 * sizeof(float) * (size_t)N_EDGE * BATCH, stream);
    (void)hipMemsetAsync(counts, 0, sizeof(int) * N_CHK, stream);

    k_count<<<(N_EDGE + 255) / 256, 256, 0, stream>>>(edge_chk, counts);
    k_scan<<<1, 1024, 0, stream>>>(counts, ptr, fill);
    k_scatter<<<(N_EDGE + 255) / 256, 256, 0, stream>>>(edge_chk, fill, edges);

    for (int t = 0; t < T_ITERS; ++t) {
        k_var<<<(N_VAR * BATCH / 4) / 256, 256, 0, stream>>>(chn, gamma_logit,
                                                             msg_C2V, msg_V2C, out, t);
        k_chk<<<N_CHK, 128, 0, stream>>>(msg_V2C, msg_C2V, ptr, edges);
    }
    k_out_final<<<(N_VAR * BATCH / 4) / 256, 256, 0, stream>>>(chn, msg_C2V, out);
}

// Round 4
// 698.908 us; speedup vs baseline: 1.7291x; 1.1144x over previous
//
#include <hip/hip_runtime.h>
#include <math.h>

#define N_VAR 8192
#define N_CHK 4096
#define DV 3
#define N_EDGE (N_VAR * DV)
#define BATCH 128
#define T_ITERS 30
#define ELLW 32

#define LOG2E 1.44269504088896340736f
#define LN2   0.69314718055994530942f
#define LN_EPS -16.118095651f   /* ln(1e-7) */

typedef float v4f __attribute__((ext_vector_type(4)));

__device__ __forceinline__ float fast_exp(float x) {   // e^x
    return __builtin_amdgcn_exp2f(x * LOG2E);
}

// log|tanh(x/2)| with x pre-clipped to [-15,15]; u = |x|
__device__ __forceinline__ float log_tanh_half(float u) {
    float E = __builtin_amdgcn_exp2f(-u * LOG2E);          // e^-u
    float la_big = (__builtin_amdgcn_logf(1.0f - E) -
                    __builtin_amdgcn_logf(1.0f + E)) * LN2;
    // small-u: tanh(z) = z(1 - z^2/3 + 2 z^4/15), z = u/2
    float z = 0.5f * u;
    float zz = z * z;
    float ts = z * (1.0f - zz * (0.33333333f - 0.13333333f * zz));
    float la_small = __builtin_amdgcn_logf(ts) * LN2;
    float la = (u < 0.25f) ? la_small : la_big;
    return fmaxf(la, LN_EPS);
}

// 2*atanh(e^L) for L <= 0, clipped like the reference
__device__ __forceinline__ float back_transform(float L) {
    float p = __builtin_amdgcn_exp2f(L * LOG2E);
    p = fminf(p, 1.0f - 1e-7f);
    return (__builtin_amdgcn_logf(1.0f + p) -
            __builtin_amdgcn_logf(1.0f - p)) * LN2;
}

// ---------------- ELL build (once per launch; edge_chk is random) ----------
// ell[c*ELLW + slot] = edge id; deg_arr[c] = degree. ell pre-zeroed: pad slots
// read edge 0's row (valid memory); their values are never consumed.

__global__ void k_ell_scatter(const int* __restrict__ edge_chk,
                              int* __restrict__ deg_arr, int* __restrict__ ell) {
    int e = blockIdx.x * blockDim.x + threadIdx.x;
    if (e < N_EDGE) {
        int c = edge_chk[e];
        int pos = atomicAdd(&deg_arr[c], 1);
        if (pos < ELLW) ell[c * ELLW + pos] = e;
    }
}

// ---------------- Variable-node update, float4 over batch ------------------

__global__ __launch_bounds__(256) void k_var(const float* __restrict__ chn,
                                             const float* __restrict__ gamma_logit,
                                             const float* __restrict__ msg_C2V,
                                             float* __restrict__ msg_V2C,
                                             float* __restrict__ out, int iter) {
    int gid = blockIdx.x * 256 + threadIdx.x;     // 0 .. N_VAR*BATCH/4
    int v = gid >> 5;                              // / 32
    int q = gid & 31;                              // float4 index in batch
    float g = 1.0f / (1.0f + fast_exp(-gamma_logit[0]));
    float om = 1.0f - g;

    const v4f* c2v = (const v4f*)msg_C2V;
    v4f* v2c = (v4f*)msg_V2C;
    int e0 = v * DV;
    int i0 = (e0 + 0) * (BATCH / 4) + q;
    int i1 = (e0 + 1) * (BATCH / 4) + q;
    int i2 = (e0 + 2) * (BATCH / 4) + q;
    v4f c0 = c2v[i0];
    v4f c1 = c2v[i1];
    v4f c2 = c2v[i2];
    v4f ch = ((const v4f*)chn)[v * (BATCH / 4) + q];
    v4f tot = ch + c0 + c1 + c2;
    if (iter > 0) {
        v4f* o = (v4f*)(out + (size_t)(iter - 1) * (N_VAR * BATCH));
        __builtin_nontemporal_store(tot, &o[v * (BATCH / 4) + q]);
    }
    v4f o0 = v2c[i0];
    v4f o1 = v2c[i1];
    v4f o2 = v2c[i2];
    v2c[i0] = g * (tot - c0) + om * o0;
    v2c[i1] = g * (tot - c1) + om * o1;
    v2c[i2] = g * (tot - c2) + om * o2;
}

// ---------------- Check-node update: ELL, unrolled loads, Duff compute -----

__global__ __launch_bounds__(128) void k_chk(const float* __restrict__ msg_V2C,
                                             float* __restrict__ msg_C2V,
                                             const int* __restrict__ deg_arr,
                                             const int* __restrict__ ell) {
    int c = blockIdx.x;
    int b = threadIdx.x;
    int deg = deg_arr[c];
    if (deg > ELLW) deg = ELLW;

    int e[ELLW];
#pragma unroll
    for (int j = 0; j < ELLW; ++j) e[j] = ell[c * ELLW + j];

    // issue all gathers unconditionally — independent, overlap in flight
    float x[ELLW];
#pragma unroll
    for (int j = 0; j < ELLW; ++j) x[j] = msg_V2C[e[j] * BATCH + b];

    float la[ELLW];
    float sum_log = 0.0f;
    unsigned mask = 0u;

#define P1(J) { float xx = fminf(fmaxf(x[J], -15.0f), 15.0f);                 \
                la[J] = log_tanh_half(fabsf(xx));                             \
                sum_log += la[J];                                             \
                mask |= (unsigned)(xx < 0.0f ? 1u : 0u) << (J); }
    switch (deg) {
      case 32: P1(31) [[fallthrough]]; case 31: P1(30) [[fallthrough]];
      case 30: P1(29) [[fallthrough]]; case 29: P1(28) [[fallthrough]];
      case 28: P1(27) [[fallthrough]]; case 27: P1(26) [[fallthrough]];
      case 26: P1(25) [[fallthrough]]; case 25: P1(24) [[fallthrough]];
      case 24: P1(23) [[fallthrough]]; case 23: P1(22) [[fallthrough]];
      case 22: P1(21) [[fallthrough]]; case 21: P1(20) [[fallthrough]];
      case 20: P1(19) [[fallthrough]]; case 19: P1(18) [[fallthrough]];
      case 18: P1(17) [[fallthrough]]; case 17: P1(16) [[fallthrough]];
      case 16: P1(15) [[fallthrough]]; case 15: P1(14) [[fallthrough]];
      case 14: P1(13) [[fallthrough]]; case 13: P1(12) [[fallthrough]];
      case 12: P1(11) [[fallthrough]]; case 11: P1(10) [[fallthrough]];
      case 10: P1(9)  [[fallthrough]]; case 9:  P1(8)  [[fallthrough]];
      case 8:  P1(7)  [[fallthrough]]; case 7:  P1(6)  [[fallthrough]];
      case 6:  P1(5)  [[fallthrough]]; case 5:  P1(4)  [[fallthrough]];
      case 4:  P1(3)  [[fallthrough]]; case 3:  P1(2)  [[fallthrough]];
      case 2:  P1(1)  [[fallthrough]]; case 1:  P1(0)  [[fallthrough]];
      default: break;
    }
#undef P1

    int totneg = __popc(mask);

#define P2(J) { float m = back_transform(sum_log - la[J]);                    \
                int par = (totneg - (int)((mask >> (J)) & 1u)) & 1;           \
                msg_C2V[e[J] * BATCH + b] = par ? -m : m; }
    switch (deg) {
      case 32: P2(31) [[fallthrough]]; case 31: P2(30) [[fallthrough]];
      case 30: P2(29) [[fallthrough]]; case 29: P2(28) [[fallthrough]];
      case 28: P2(27) [[fallthrough]]; case 27: P2(26) [[fallthrough]];
      case 26: P2(25) [[fallthrough]]; case 25: P2(24) [[fallthrough]];
      case 24: P2(23) [[fallthrough]]; case 23: P2(22) [[fallthrough]];
      case 22: P2(21) [[fallthrough]]; case 21: P2(20) [[fallthrough]];
      case 20: P2(19) [[fallthrough]]; case 19: P2(18) [[fallthrough]];
      case 18: P2(17) [[fallthrough]]; case 17: P2(16) [[fallthrough]];
      case 16: P2(15) [[fallthrough]]; case 15: P2(14) [[fallthrough]];
      case 14: P2(13) [[fallthrough]]; case 13: P2(12) [[fallthrough]];
      case 12: P2(11) [[fallthrough]]; case 11: P2(10) [[fallthrough]];
      case 10: P2(9)  [[fallthrough]]; case 9:  P2(8)  [[fallthrough]];
      case 8:  P2(7)  [[fallthrough]]; case 7:  P2(6)  [[fallthrough]];
      case 6:  P2(5)  [[fallthrough]]; case 5:  P2(4)  [[fallthrough]];
      case 4:  P2(3)  [[fallthrough]]; case 3:  P2(2)  [[fallthrough]];
      case 2:  P2(1)  [[fallthrough]]; case 1:  P2(0)  [[fallthrough]];
      default: break;
    }
#undef P2
}

// ---------------- Final posterior (out[T-1]) -------------------------------

__global__ __launch_bounds__(256) void k_out_final(const float* __restrict__ chn,
                                                   const float* __restrict__ msg_C2V,
                                                   float* __restrict__ out) {
    int gid = blockIdx.x * 256 + threadIdx.x;
    int v = gid >> 5;
    int q = gid & 31;
    const v4f* c2v = (const v4f*)msg_C2V;
    int e0 = v * DV;
    v4f c0 = c2v[(e0 + 0) * (BATCH / 4) + q];
    v4f c1 = c2v[(e0 + 1) * (BATCH / 4) + q];
    v4f c2 = c2v[(e0 + 2) * (BATCH / 4) + q];
    v4f ch = ((const v4f*)chn)[v * (BATCH / 4) + q];
    v4f tot = ch + c0 + c1 + c2;
    v4f* o = (v4f*)(out + (size_t)(T_ITERS - 1) * (N_VAR * BATCH));
    __builtin_nontemporal_store(tot, &o[v * (BATCH / 4) + q]);
}

// ---------------- Launch ---------------------------------------------------

extern "C" void kernel_launch(void* const* d_in, const int* in_sizes, int n_in,
                              void* d_out, int out_size, void* d_ws, size_t ws_size,
                              hipStream_t stream) {
    const float* chn         = (const float*)d_in[0];
    const float* gamma_logit = (const float*)d_in[1];
    // d_in[2] = edge_var (deterministic: e/3) — not needed
    const int* edge_chk      = (const int*)d_in[3];
    float* out = (float*)d_out;

    const size_t MSG_ROWS = N_EDGE;  // k_chk never reads out of [0, N_EDGE)
    float* msg_C2V = (float*)d_ws;
    float* msg_V2C = msg_C2V + MSG_ROWS * BATCH;
    int* ell     = (int*)(msg_V2C + MSG_ROWS * BATCH);
    int* deg_arr = ell + (size_t)N_CHK * ELLW;

    (void)hipMemsetAsync(msg_C2V, 0, 2 * sizeof(float) * MSG_ROWS * BATCH, stream);
    (void)hipMemsetAsync(ell, 0, sizeof(int) * ((size_t)N_CHK * ELLW + N_CHK), stream);

    k_ell_scatter<<<(N_EDGE + 255) / 256, 256, 0, stream>>>(edge_chk, deg_arr, ell);

    for (int t = 0; t < T_ITERS; ++t) {
        k_var<<<(N_VAR * BATCH / 4) / 256, 256, 0, stream>>>(chn, gamma_logit,
                                                             msg_C2V, msg_V2C, out, t);
        k_chk<<<N_CHK, 128, 0, stream>>>(msg_V2C, msg_C2V, deg_arr, ell);
    }
    k_out_final<<<(N_VAR * BATCH / 4) / 256, 256, 0, stream>>>(chn, msg_C2V, out);
}